// Round 2
// baseline (343.843 us; speedup 1.0000x reference)
//
#include <hip/hip_runtime.h>
#include <hip/hip_bf16.h>

typedef unsigned short ushort_t;
typedef __attribute__((ext_vector_type(8))) short bf16x8;
typedef __attribute__((ext_vector_type(4))) float f32x4;

#define B_SZ 4096
#define N_SZ 8
#define D_SZ 256
#define FF_SZ 2048
#define M_SZ (B_SZ * N_SZ)   // 32768
#define WELEM (D_SZ * D_SZ * N_SZ)  // 524288

__device__ inline float b2f(ushort_t u) {
    union { unsigned int i; float f; } t; t.i = ((unsigned int)u) << 16; return t.f;
}
__device__ inline ushort_t f2b(float f) {
    union { unsigned int i; float f; } t; t.f = f;
    unsigned int i = t.i;
    unsigned int r = (i + 0x7fffu + ((i >> 16) & 1u)) >> 16;
    return (ushort_t)r;
}

// ---------------- convert/repack all weights f32 -> bf16
// seg 0: bt_in[d2*2048 + s*256 + d1]  = w_in [d1*2048 + d2*8 + s]
// seg 1: bt_out[...]                  = w_out[...]
// seg 2: W1b[i] = W1[i]   (2048x256, already [n][k] layout)
// seg 3: W2b[i] = W2[i]   (256x2048, already [n][k] layout)
__global__ __launch_bounds__(256) void convert_weights(const float* __restrict__ w_in,
                                                       const float* __restrict__ w_out,
                                                       const float* __restrict__ W1,
                                                       const float* __restrict__ W2,
                                                       ushort_t* __restrict__ bt_in,
                                                       ushort_t* __restrict__ bt_out,
                                                       ushort_t* __restrict__ W1b,
                                                       ushort_t* __restrict__ W2b) {
    int idx = blockIdx.x * 256 + threadIdx.x;
    int seg = idx / WELEM;
    int r = idx - seg * WELEM;
    if (seg == 0 || seg == 1) {
        const float* w = (seg == 0) ? w_in : w_out;
        ushort_t* bt = (seg == 0) ? bt_in : bt_out;
        int d1 = r & 255, s = (r >> 8) & 7, d2 = r >> 11;
        bt[r] = f2b(w[d1 * 2048 + d2 * 8 + s]);
    } else {
        const float* w = (seg == 2) ? W1 : W2;
        ushort_t* o = (seg == 2) ? W1b : W2b;
        o[r] = f2b(w[r]);
    }
}

// ---------------- layernorm: one block (256 threads) per row of 256, f32 in -> bf16 out
__global__ __launch_bounds__(256) void ln_kernel(const float* __restrict__ xin,
                                                 const float* __restrict__ gam,
                                                 const float* __restrict__ bet,
                                                 ushort_t* __restrict__ out) {
    int row = blockIdx.x;
    int t = threadIdx.x;
    float v = xin[(size_t)row * 256 + t];
    float s = v, q = v * v;
#pragma unroll
    for (int off = 1; off < 64; off <<= 1) {
        s += __shfl_xor(s, off, 64);
        q += __shfl_xor(q, off, 64);
    }
    __shared__ float ss[4], sq[4];
    int wave = t >> 6;
    if ((t & 63) == 0) { ss[wave] = s; sq[wave] = q; }
    __syncthreads();
    float S = ss[0] + ss[1] + ss[2] + ss[3];
    float Q = sq[0] + sq[1] + sq[2] + sq[3];
    float mu = S * (1.0f / 256.0f);
    float var = Q * (1.0f / 256.0f) - mu * mu;
    float rs = rsqrtf(var + 1e-5f);
    float y = (v - mu) * rs * gam[t] + bet[t];
    out[(size_t)row * 256 + t] = f2b(y);
}

// ---------------- GEMM core: C[M,N] = A[M,K] @ Bt[N,K]^T, 128x128 tile, BK=32
// MODE 0: TT   (A = gathered xn, K=2048, N=256, epi: +ent(f32) -> x f32)
// MODE 1: FF1  (A = yn, K=256, N=2048, epi: +bias1, relu -> h1 bf16)
// MODE 2: FF2  (A = h1, K=2048, N=256, epi: +bias2 +x(f32) -> out f32)
template <int MODE, int K>
__global__ __launch_bounds__(256) void gemm_k(const ushort_t* __restrict__ A,
                                              const ushort_t* __restrict__ Bt0,
                                              const ushort_t* __restrict__ Bt1,
                                              const float* __restrict__ bias,
                                              const float* __restrict__ res,
                                              float* __restrict__ outf,
                                              ushort_t* __restrict__ outb) {
    __shared__ __attribute__((aligned(16))) ushort_t As[128][56];
    __shared__ __attribute__((aligned(16))) ushort_t Bs[128][56];

    const int t = threadIdx.x;
    const int m0 = blockIdx.y * 128;
    const int n0 = blockIdx.x * 128;
    const int lane = t & 63;
    const int wave = t >> 6;
    const int wr = wave & 1, wc = wave >> 1;
    const int l16 = lane & 15, quad = lane >> 4;

    const ushort_t* Bt = (MODE == 0 && m0 >= M_SZ / 2) ? Bt1 : Bt0;

    f32x4 acc[4][4];
#pragma unroll
    for (int i = 0; i < 4; i++)
#pragma unroll
        for (int j = 0; j < 4; j++) acc[i][j] = (f32x4)(0.0f);

    const int srow = t >> 1;           // 0..127
    const int shalf = (t & 1) * 16;    // 0 or 16 (elements)

    for (int kt = 0; kt < K / 32; ++kt) {
        const int kg = kt * 32;
        const ushort_t* ga;
        if (MODE == 0) {
            int m = m0 + srow; int b = m >> 3; int n = m & 7;
            int s = kg >> 8;        // shift segment
            int dp = kg & 255;      // offset within segment
            ga = A + ((size_t)(b * 8 + ((n - s) & 7)) * 256 + dp + shalf);
        } else {
            ga = A + (size_t)(m0 + srow) * K + kg + shalf;
        }
        const ushort_t* gb = Bt + (size_t)(n0 + srow) * K + kg + shalf;
        uint4 av0 = *(const uint4*)(ga);
        uint4 av1 = *(const uint4*)(ga + 8);
        uint4 bv0 = *(const uint4*)(gb);
        uint4 bv1 = *(const uint4*)(gb + 8);
        __syncthreads();
        *(uint4*)&As[srow][shalf]     = av0;
        *(uint4*)&As[srow][shalf + 8] = av1;
        *(uint4*)&Bs[srow][shalf]     = bv0;
        *(uint4*)&Bs[srow][shalf + 8] = bv1;
        __syncthreads();

        bf16x8 af[4], bfv[4];
#pragma unroll
        for (int i = 0; i < 4; i++) af[i]  = *(const bf16x8*)&As[wr * 64 + i * 16 + l16][quad * 8];
#pragma unroll
        for (int j = 0; j < 4; j++) bfv[j] = *(const bf16x8*)&Bs[wc * 64 + j * 16 + l16][quad * 8];
#pragma unroll
        for (int i = 0; i < 4; i++)
#pragma unroll
            for (int j = 0; j < 4; j++)
                acc[i][j] = __builtin_amdgcn_mfma_f32_16x16x32_bf16(af[i], bfv[j], acc[i][j], 0, 0, 0);
    }

    // epilogue: C row = quad*4 + reg, col = l16 within each 16x16 frag
#pragma unroll
    for (int i = 0; i < 4; i++) {
#pragma unroll
        for (int j = 0; j < 4; j++) {
            int r0 = m0 + wr * 64 + i * 16 + quad * 4;
            int c = n0 + wc * 64 + j * 16 + l16;
#pragma unroll
            for (int r = 0; r < 4; r++) {
                float v = acc[i][j][r];
                if (MODE == 0) {
                    size_t o = (size_t)(r0 + r) * 256 + c;
                    outf[o] = v + res[o];
                } else if (MODE == 1) {
                    size_t o = (size_t)(r0 + r) * 2048 + c;
                    v += bias[c];
                    v = v > 0.0f ? v : 0.0f;
                    outb[o] = f2b(v);
                } else {
                    size_t o = (size_t)(r0 + r) * 256 + c;
                    v += bias[c] + res[o];
                    outf[o] = v;
                }
            }
        }
    }
}

extern "C" void kernel_launch(void* const* d_in, const int* in_sizes, int n_in,
                              void* d_out, int out_size, void* d_ws, size_t ws_size,
                              hipStream_t stream) {
    const float* ent   = (const float*)d_in[0];
    const float* w_in  = (const float*)d_in[1];
    const float* w_out = (const float*)d_in[2];
    const float* W1    = (const float*)d_in[3];
    const float* bias1 = (const float*)d_in[4];
    const float* W2    = (const float*)d_in[5];
    const float* bias2 = (const float*)d_in[6];
    const float* g1    = (const float*)d_in[7];
    const float* be1   = (const float*)d_in[8];
    const float* g2    = (const float*)d_in[9];
    const float* be2   = (const float*)d_in[10];
    float* out = (float*)d_out;

    char* ws = (char*)d_ws;
    // layout (bytes):
    //   xn/yn bf16 : 32768*256*2  = 16,777,216
    //   x     f32  : 32768*256*4  = 33,554,432
    //   h1    bf16 : 32768*2048*2 = 134,217,728
    //   bt_in/bt_out/W1b/W2b bf16 : 4 * 1,048,576
    ushort_t* xn     = (ushort_t*)ws;                              // also yn (aliased after TT)
    float*    x      = (float*)(ws + 16777216);
    ushort_t* h1     = (ushort_t*)(ws + 16777216 + 33554432);
    ushort_t* bt_in  = (ushort_t*)(ws + 16777216 + 33554432 + 134217728);
    ushort_t* bt_out = bt_in + WELEM;
    ushort_t* W1b    = bt_out + WELEM;
    ushort_t* W2b    = W1b + WELEM;

    // 1) convert + repack all weights to bf16
    hipLaunchKernelGGL(convert_weights, dim3(4 * WELEM / 256), dim3(256), 0, stream,
                       w_in, w_out, W1, W2, bt_in, bt_out, W1b, W2b);
    // 2) LN1: ent -> xn (bf16)
    hipLaunchKernelGGL(ln_kernel, dim3(M_SZ), dim3(256), 0, stream, ent, g1, be1, xn);
    // 3) TT gemm: x = ent + gather(xn) @ bt  (f32 out)
    hipLaunchKernelGGL((gemm_k<0, 2048>), dim3(2, 256), dim3(256), 0, stream,
                       xn, bt_in, bt_out, (const float*)nullptr, ent, x, (ushort_t*)nullptr);
    // 4) LN2: x -> yn (bf16, aliases xn)
    hipLaunchKernelGGL(ln_kernel, dim3(M_SZ), dim3(256), 0, stream, x, g2, be2, xn);
    // 5) FF1: h1 = relu(yn @ W1b^T + bias1)  (bf16)
    hipLaunchKernelGGL((gemm_k<1, 256>), dim3(16, 256), dim3(256), 0, stream,
                       xn, W1b, (const ushort_t*)nullptr, bias1, (const float*)nullptr,
                       (float*)nullptr, h1);
    // 6) FF2: out = x + h1 @ W2b^T + bias2  (f32)
    hipLaunchKernelGGL((gemm_k<2, 2048>), dim3(2, 256), dim3(256), 0, stream,
                       h1, W2b, (const ushort_t*)nullptr, bias2, x, out, (ushort_t*)nullptr);
}

// Round 3
// 325.840 us; speedup vs baseline: 1.0552x; 1.0552x over previous
//
#include <hip/hip_runtime.h>
#include <hip/hip_bf16.h>

typedef unsigned short ushort_t;
typedef __attribute__((ext_vector_type(8))) short bf16x8;
typedef __attribute__((ext_vector_type(4))) float f32x4;

#define B_SZ 4096
#define N_SZ 8
#define D_SZ 256
#define FF_SZ 2048
#define M_SZ (B_SZ * N_SZ)   // 32768
#define WELEM (D_SZ * D_SZ * N_SZ)  // 524288

__device__ inline float b2f(ushort_t u) {
    union { unsigned int i; float f; } t; t.i = ((unsigned int)u) << 16; return t.f;
}
__device__ inline ushort_t f2b(float f) {
    union { unsigned int i; float f; } t; t.f = f;
    unsigned int i = t.i;
    unsigned int r = (i + 0x7fffu + ((i >> 16) & 1u)) >> 16;
    return (ushort_t)r;
}

// async global->LDS, 16B per lane; LDS dest must be wave-uniform base + lane*16
__device__ inline void gl2lds16(const ushort_t* g, ushort_t* l) {
    __builtin_amdgcn_global_load_lds((const __attribute__((address_space(1))) void*)g,
                                     (__attribute__((address_space(3))) void*)l, 16, 0, 0);
}

// ---------------- convert/repack all weights f32 -> bf16
__global__ __launch_bounds__(256) void convert_weights(const float* __restrict__ w_in,
                                                       const float* __restrict__ w_out,
                                                       const float* __restrict__ W1,
                                                       const float* __restrict__ W2,
                                                       ushort_t* __restrict__ bt_in,
                                                       ushort_t* __restrict__ bt_out,
                                                       ushort_t* __restrict__ W1b,
                                                       ushort_t* __restrict__ W2b) {
    int idx = blockIdx.x * 256 + threadIdx.x;
    int seg = idx / WELEM;
    int r = idx - seg * WELEM;
    if (seg == 0 || seg == 1) {
        const float* w = (seg == 0) ? w_in : w_out;
        ushort_t* bt = (seg == 0) ? bt_in : bt_out;
        int d1 = r & 255, s = (r >> 8) & 7, d2 = r >> 11;
        bt[r] = f2b(w[d1 * 2048 + d2 * 8 + s]);
    } else {
        const float* w = (seg == 2) ? W1 : W2;
        ushort_t* o = (seg == 2) ? W1b : W2b;
        o[r] = f2b(w[r]);
    }
}

// ---------------- layernorm: one block (256 threads) per row of 256, f32 in -> bf16 out
__global__ __launch_bounds__(256) void ln_kernel(const float* __restrict__ xin,
                                                 const float* __restrict__ gam,
                                                 const float* __restrict__ bet,
                                                 ushort_t* __restrict__ out) {
    int row = blockIdx.x;
    int t = threadIdx.x;
    float v = xin[(size_t)row * 256 + t];
    float s = v, q = v * v;
#pragma unroll
    for (int off = 1; off < 64; off <<= 1) {
        s += __shfl_xor(s, off, 64);
        q += __shfl_xor(q, off, 64);
    }
    __shared__ float ss[4], sq[4];
    int wave = t >> 6;
    if ((t & 63) == 0) { ss[wave] = s; sq[wave] = q; }
    __syncthreads();
    float S = ss[0] + ss[1] + ss[2] + ss[3];
    float Q = sq[0] + sq[1] + sq[2] + sq[3];
    float mu = S * (1.0f / 256.0f);
    float var = Q * (1.0f / 256.0f) - mu * mu;
    float rs = rsqrtf(var + 1e-5f);
    float y = (v - mu) * rs * gam[t] + bet[t];
    out[(size_t)row * 256 + t] = f2b(y);
}

// ---------------- GEMM core: C[M,N] = A[M,K] @ Bt[N,K]^T, 128x128 tile, BK=32
// LDS layout: unpadded [128][32] (64 B rows), staged via global_load_lds width=16.
// Thread t stages row t/4, cols (t&3)*8..+7 (inst 0: rows 0-63; inst 1: rows 64-127).
// MODE 0: TT   (A = gathered xn, epi: +ent(f32) -> x f32)
// MODE 1: FF1  (epi: +bias1, relu -> h1 bf16)
// MODE 2: FF2  (epi: +bias2 +x(f32) -> out f32)
template <int MODE, int K>
__global__ __launch_bounds__(256) void gemm_k(const ushort_t* __restrict__ A,
                                              const ushort_t* __restrict__ Bt0,
                                              const ushort_t* __restrict__ Bt1,
                                              const float* __restrict__ bias,
                                              const float* __restrict__ res,
                                              float* __restrict__ outf,
                                              ushort_t* __restrict__ outb) {
    __shared__ __attribute__((aligned(16))) ushort_t As[128 * 32];
    __shared__ __attribute__((aligned(16))) ushort_t Bs[128 * 32];

    const int t = threadIdx.x;
    const int m0 = blockIdx.y * 128;
    const int n0 = blockIdx.x * 128;
    const int lane = t & 63;
    const int wave = t >> 6;
    const int wr = wave & 1, wc = wave >> 1;
    const int l16 = lane & 15, quad = lane >> 4;

    const ushort_t* Bt = (MODE == 0 && m0 >= M_SZ / 2) ? Bt1 : Bt0;

    f32x4 acc[4][4];
#pragma unroll
    for (int i = 0; i < 4; i++)
#pragma unroll
        for (int j = 0; j < 4; j++) acc[i][j] = (f32x4)(0.0f);

    const int ra = t >> 2;          // staging row 0..63
    const int colc = (t & 3) << 3;  // staging col chunk 0,8,16,24

    // per-thread LDS destinations (wave-uniform base + lane*16 by construction)
    ushort_t* lA0 = As + t * 8;
    ushort_t* lA1 = As + 2048 + t * 8;
    ushort_t* lB0 = Bs + t * 8;
    ushort_t* lB1 = Bs + 2048 + t * 8;

    for (int kt = 0; kt < K / 32; ++kt) {
        const int kg = kt * 32;
        const ushort_t *gA0, *gA1;
        if (MODE == 0) {
            const int s = kg >> 8;
            const int dp = (kg & 255) + colc;
            const int m1 = m0 + ra, m2 = m0 + 64 + ra;
            gA0 = A + ((size_t)((m1 >> 3) * 8 + (((m1 & 7) - s) & 7)) * 256 + dp);
            gA1 = A + ((size_t)((m2 >> 3) * 8 + (((m2 & 7) - s) & 7)) * 256 + dp);
        } else {
            gA0 = A + (size_t)(m0 + ra) * K + kg + colc;
            gA1 = gA0 + (size_t)64 * K;
        }
        const ushort_t* gB0 = Bt + (size_t)(n0 + ra) * K + kg + colc;
        const ushort_t* gB1 = gB0 + (size_t)64 * K;

        __syncthreads();            // previous iter's ds_reads complete before overwrite
        gl2lds16(gA0, lA0);
        gl2lds16(gA1, lA1);
        gl2lds16(gB0, lB0);
        gl2lds16(gB1, lB1);
        __syncthreads();            // staging complete (vmcnt drained by compiler)

        bf16x8 af[4], bfv[4];
#pragma unroll
        for (int i = 0; i < 4; i++) af[i]  = *(const bf16x8*)&As[(wr * 64 + i * 16 + l16) * 32 + quad * 8];
#pragma unroll
        for (int j = 0; j < 4; j++) bfv[j] = *(const bf16x8*)&Bs[(wc * 64 + j * 16 + l16) * 32 + quad * 8];
#pragma unroll
        for (int i = 0; i < 4; i++)
#pragma unroll
            for (int j = 0; j < 4; j++)
                acc[i][j] = __builtin_amdgcn_mfma_f32_16x16x32_bf16(af[i], bfv[j], acc[i][j], 0, 0, 0);
    }

    // epilogue: C row = quad*4 + reg, col = l16 within each 16x16 frag
#pragma unroll
    for (int i = 0; i < 4; i++) {
#pragma unroll
        for (int j = 0; j < 4; j++) {
            int r0 = m0 + wr * 64 + i * 16 + quad * 4;
            int c = n0 + wc * 64 + j * 16 + l16;
#pragma unroll
            for (int r = 0; r < 4; r++) {
                float v = acc[i][j][r];
                if (MODE == 0) {
                    size_t o = (size_t)(r0 + r) * 256 + c;
                    outf[o] = v + res[o];
                } else if (MODE == 1) {
                    size_t o = (size_t)(r0 + r) * 2048 + c;
                    v += bias[c];
                    v = v > 0.0f ? v : 0.0f;
                    outb[o] = f2b(v);
                } else {
                    size_t o = (size_t)(r0 + r) * 256 + c;
                    v += bias[c] + res[o];
                    outf[o] = v;
                }
            }
        }
    }
}

extern "C" void kernel_launch(void* const* d_in, const int* in_sizes, int n_in,
                              void* d_out, int out_size, void* d_ws, size_t ws_size,
                              hipStream_t stream) {
    const float* ent   = (const float*)d_in[0];
    const float* w_in  = (const float*)d_in[1];
    const float* w_out = (const float*)d_in[2];
    const float* W1    = (const float*)d_in[3];
    const float* bias1 = (const float*)d_in[4];
    const float* W2    = (const float*)d_in[5];
    const float* bias2 = (const float*)d_in[6];
    const float* g1    = (const float*)d_in[7];
    const float* be1   = (const float*)d_in[8];
    const float* g2    = (const float*)d_in[9];
    const float* be2   = (const float*)d_in[10];
    float* out = (float*)d_out;

    char* ws = (char*)d_ws;
    ushort_t* xn     = (ushort_t*)ws;                              // also yn (aliased after TT)
    float*    x      = (float*)(ws + 16777216);
    ushort_t* h1     = (ushort_t*)(ws + 16777216 + 33554432);
    ushort_t* bt_in  = (ushort_t*)(ws + 16777216 + 33554432 + 134217728);
    ushort_t* bt_out = bt_in + WELEM;
    ushort_t* W1b    = bt_out + WELEM;
    ushort_t* W2b    = W1b + WELEM;

    // 1) convert + repack all weights to bf16
    hipLaunchKernelGGL(convert_weights, dim3(4 * WELEM / 256), dim3(256), 0, stream,
                       w_in, w_out, W1, W2, bt_in, bt_out, W1b, W2b);
    // 2) LN1: ent -> xn (bf16)
    hipLaunchKernelGGL(ln_kernel, dim3(M_SZ), dim3(256), 0, stream, ent, g1, be1, xn);
    // 3) TT gemm: x = ent + gather(xn) @ bt  (f32 out)
    hipLaunchKernelGGL((gemm_k<0, 2048>), dim3(2, 256), dim3(256), 0, stream,
                       xn, bt_in, bt_out, (const float*)nullptr, ent, x, (ushort_t*)nullptr);
    // 4) LN2: x -> yn (bf16, aliases xn)
    hipLaunchKernelGGL(ln_kernel, dim3(M_SZ), dim3(256), 0, stream, x, g2, be2, xn);
    // 5) FF1: h1 = relu(yn @ W1b^T + bias1)  (bf16)
    hipLaunchKernelGGL((gemm_k<1, 256>), dim3(16, 256), dim3(256), 0, stream,
                       xn, W1b, (const ushort_t*)nullptr, bias1, (const float*)nullptr,
                       (float*)nullptr, h1);
    // 6) FF2: out = x + h1 @ W2b^T + bias2  (f32)
    hipLaunchKernelGGL((gemm_k<2, 2048>), dim3(2, 256), dim3(256), 0, stream,
                       h1, W2b, (const ushort_t*)nullptr, bias2, x, out, (ushort_t*)nullptr);
}

// Round 4
// 294.778 us; speedup vs baseline: 1.1664x; 1.1054x over previous
//
#include <hip/hip_runtime.h>
#include <hip/hip_bf16.h>

typedef unsigned short ushort_t;
typedef __attribute__((ext_vector_type(8))) short bf16x8;
typedef __attribute__((ext_vector_type(4))) float f32x4;

#define B_SZ 4096
#define N_SZ 8
#define D_SZ 256
#define FF_SZ 2048
#define M_SZ (B_SZ * N_SZ)   // 32768
#define WELEM (D_SZ * D_SZ * N_SZ)  // 524288

__device__ inline float b2f(ushort_t u) {
    union { unsigned int i; float f; } t; t.i = ((unsigned int)u) << 16; return t.f;
}
__device__ inline ushort_t f2b(float f) {
    union { unsigned int i; float f; } t; t.f = f;
    unsigned int i = t.i;
    unsigned int r = (i + 0x7fffu + ((i >> 16) & 1u)) >> 16;
    return (ushort_t)r;
}

// async global->LDS, 16B per lane; LDS dest must be wave-uniform base + lane*16
__device__ inline void gl2lds16(const ushort_t* g, ushort_t* l) {
    __builtin_amdgcn_global_load_lds((const __attribute__((address_space(1))) void*)g,
                                     (__attribute__((address_space(3))) void*)l, 16, 0, 0);
}

// ---------------- convert/repack all weights f32 -> bf16
__global__ __launch_bounds__(256) void convert_weights(const float* __restrict__ w_in,
                                                       const float* __restrict__ w_out,
                                                       const float* __restrict__ W1,
                                                       const float* __restrict__ W2,
                                                       ushort_t* __restrict__ bt_in,
                                                       ushort_t* __restrict__ bt_out,
                                                       ushort_t* __restrict__ W1b,
                                                       ushort_t* __restrict__ W2b) {
    int idx = blockIdx.x * 256 + threadIdx.x;
    int seg = idx / WELEM;
    int r = idx - seg * WELEM;
    if (seg == 0 || seg == 1) {
        const float* w = (seg == 0) ? w_in : w_out;
        ushort_t* bt = (seg == 0) ? bt_in : bt_out;
        int d1 = r & 255, s = (r >> 8) & 7, d2 = r >> 11;
        bt[r] = f2b(w[d1 * 2048 + d2 * 8 + s]);
    } else {
        const float* w = (seg == 2) ? W1 : W2;
        ushort_t* o = (seg == 2) ? W1b : W2b;
        o[r] = f2b(w[r]);
    }
}

// ---------------- LN1: one WAVE per row of 256, float4 loads, shuffle-only reduce
__global__ __launch_bounds__(256) void ln_fast(const float* __restrict__ xin,
                                               const float* __restrict__ gam,
                                               const float* __restrict__ bet,
                                               ushort_t* __restrict__ out) {
    const int wave = threadIdx.x >> 6;
    const int lane = threadIdx.x & 63;
    const size_t row = (size_t)blockIdx.x * 4 + wave;
    const float4 v = *(const float4*)&xin[row * 256 + lane * 4];
    float s = v.x + v.y + v.z + v.w;
    float q = v.x * v.x + v.y * v.y + v.z * v.z + v.w * v.w;
#pragma unroll
    for (int off = 1; off < 64; off <<= 1) {
        s += __shfl_xor(s, off, 64);
        q += __shfl_xor(q, off, 64);
    }
    const float mu = s * (1.0f / 256.0f);
    const float var = q * (1.0f / 256.0f) - mu * mu;
    const float rs = rsqrtf(var + 1e-5f);
    const float4 g = *(const float4*)&gam[lane * 4];
    const float4 b = *(const float4*)&bet[lane * 4];
    ushort4 o;
    o.x = f2b((v.x - mu) * rs * g.x + b.x);
    o.y = f2b((v.y - mu) * rs * g.y + b.y);
    o.z = f2b((v.z - mu) * rs * g.z + b.z);
    o.w = f2b((v.w - mu) * rs * g.w + b.w);
    *(ushort4*)&out[row * 256 + lane * 4] = o;
}

// ---------------- TT gemm + fused LN2: 128x256 tile, 512 threads (8 waves, 2x4)
// x = gather(xn) @ bt + ent   (f32, in-register)
// yn = LN(x; g2, be2) -> bf16 ;  xb = bf16(x) for FF2 residual
__global__ __launch_bounds__(512) void tt_ln(const ushort_t* __restrict__ A,
                                             const ushort_t* __restrict__ Bt0,
                                             const ushort_t* __restrict__ Bt1,
                                             const float* __restrict__ ent,
                                             const float* __restrict__ g2,
                                             const float* __restrict__ be2,
                                             ushort_t* __restrict__ yn,
                                             ushort_t* __restrict__ xb) {
    __shared__ __attribute__((aligned(16))) ushort_t As[128 * 32];   // 8 KB
    __shared__ __attribute__((aligned(16))) ushort_t Bs[256 * 32];   // 16 KB
    __shared__ float red_s[128 * 4];                                 // 2 KB
    __shared__ float red_q[128 * 4];                                 // 2 KB

    const int t = threadIdx.x;
    const int m0 = blockIdx.x * 128;
    const int lane = t & 63;
    const int wave = t >> 6;
    const int wr = wave & 1, wc = wave >> 1;     // wc 0..3 -> 4 x 64 cols = 256
    const int l16 = lane & 15, quad = lane >> 4;

    const ushort_t* Bt = (m0 >= M_SZ / 2) ? Bt1 : Bt0;

    f32x4 acc[4][4];
#pragma unroll
    for (int i = 0; i < 4; i++)
#pragma unroll
        for (int j = 0; j < 4; j++) acc[i][j] = (f32x4)(0.0f);

    const int ra = t >> 2;          // 0..127
    const int colc = (t & 3) << 3;  // 0,8,16,24
    const int mrow = m0 + ra;
    const int bgrp = (mrow >> 3) * 8;
    const int nn = mrow & 7;

    ushort_t* lA  = As + t * 8;
    ushort_t* lB0 = Bs + t * 8;
    ushort_t* lB1 = Bs + 4096 + t * 8;

    for (int kt = 0; kt < 64; ++kt) {
        const int kg = kt * 32;
        const int s = kg >> 8;
        const int dp = (kg & 255) + colc;
        const ushort_t* gA  = A + ((size_t)(bgrp + ((nn - s) & 7)) * 256 + dp);
        const ushort_t* gB0 = Bt + (size_t)ra * 2048 + kg + colc;
        const ushort_t* gB1 = gB0 + (size_t)128 * 2048;

        __syncthreads();
        gl2lds16(gA, lA);
        gl2lds16(gB0, lB0);
        gl2lds16(gB1, lB1);
        __syncthreads();

        bf16x8 af[4], bfv[4];
#pragma unroll
        for (int i = 0; i < 4; i++) af[i]  = *(const bf16x8*)&As[(wr * 64 + i * 16 + l16) * 32 + quad * 8];
#pragma unroll
        for (int j = 0; j < 4; j++) bfv[j] = *(const bf16x8*)&Bs[(wc * 64 + j * 16 + l16) * 32 + quad * 8];
#pragma unroll
        for (int i = 0; i < 4; i++)
#pragma unroll
            for (int j = 0; j < 4; j++)
                acc[i][j] = __builtin_amdgcn_mfma_f32_16x16x32_bf16(af[i], bfv[j], acc[i][j], 0, 0, 0);
    }

    // ---- epilogue: x = acc + ent; fused LN over each full row (256 cols in-block)
    int c[4];
#pragma unroll
    for (int j = 0; j < 4; j++) c[j] = wc * 64 + j * 16 + l16;

    // add residual, accumulate row partial sums, shuffle-reduce over l16
#pragma unroll
    for (int i = 0; i < 4; i++) {
#pragma unroll
        for (int r = 0; r < 4; r++) {
            const int rl = wr * 64 + i * 16 + quad * 4 + r;   // 0..127
            const size_t grow = (size_t)(m0 + rl) * 256;
            float s = 0.0f, q = 0.0f;
#pragma unroll
            for (int j = 0; j < 4; j++) {
                float v = acc[i][j][r] + ent[grow + c[j]];
                acc[i][j][r] = v;
                s += v;
                q += v * v;
            }
#pragma unroll
            for (int off = 1; off < 16; off <<= 1) {
                s += __shfl_xor(s, off, 64);
                q += __shfl_xor(q, off, 64);
            }
            if (l16 == 0) { red_s[rl * 4 + wc] = s; red_q[rl * 4 + wc] = q; }
        }
    }
    __syncthreads();

#pragma unroll
    for (int i = 0; i < 4; i++) {
#pragma unroll
        for (int r = 0; r < 4; r++) {
            const int rl = wr * 64 + i * 16 + quad * 4 + r;
            const size_t grow = (size_t)(m0 + rl) * 256;
            const float4 ss = *(const float4*)&red_s[rl * 4];
            const float4 qq = *(const float4*)&red_q[rl * 4];
            const float S = ss.x + ss.y + ss.z + ss.w;
            const float Q = qq.x + qq.y + qq.z + qq.w;
            const float mu = S * (1.0f / 256.0f);
            const float var = Q * (1.0f / 256.0f) - mu * mu;
            const float rs = rsqrtf(var + 1e-5f);
#pragma unroll
            for (int j = 0; j < 4; j++) {
                const float v = acc[i][j][r];
                yn[grow + c[j]] = f2b((v - mu) * rs * g2[c[j]] + be2[c[j]]);
                xb[grow + c[j]] = f2b(v);
            }
        }
    }
}

// ---------------- GEMM core: C[M,N] = A[M,K] @ Bt[N,K]^T, 128x128 tile, BK=32
// MODE 1: FF1  (epi: +bias1, relu -> h1 bf16)
// MODE 2: FF2  (epi: +bias2 + b2f(resb) -> out f32)
template <int MODE, int K>
__global__ __launch_bounds__(256) void gemm_k(const ushort_t* __restrict__ A,
                                              const ushort_t* __restrict__ Bt0,
                                              const float* __restrict__ bias,
                                              const ushort_t* __restrict__ resb,
                                              float* __restrict__ outf,
                                              ushort_t* __restrict__ outb) {
    __shared__ __attribute__((aligned(16))) ushort_t As[128 * 32];
    __shared__ __attribute__((aligned(16))) ushort_t Bs[128 * 32];

    const int t = threadIdx.x;
    const int m0 = blockIdx.y * 128;
    const int n0 = blockIdx.x * 128;
    const int lane = t & 63;
    const int wave = t >> 6;
    const int wr = wave & 1, wc = wave >> 1;
    const int l16 = lane & 15, quad = lane >> 4;

    f32x4 acc[4][4];
#pragma unroll
    for (int i = 0; i < 4; i++)
#pragma unroll
        for (int j = 0; j < 4; j++) acc[i][j] = (f32x4)(0.0f);

    const int ra = t >> 2;
    const int colc = (t & 3) << 3;

    ushort_t* lA0 = As + t * 8;
    ushort_t* lA1 = As + 2048 + t * 8;
    ushort_t* lB0 = Bs + t * 8;
    ushort_t* lB1 = Bs + 2048 + t * 8;

    for (int kt = 0; kt < K / 32; ++kt) {
        const int kg = kt * 32;
        const ushort_t* gA0 = A + (size_t)(m0 + ra) * K + kg + colc;
        const ushort_t* gA1 = gA0 + (size_t)64 * K;
        const ushort_t* gB0 = Bt0 + (size_t)(n0 + ra) * K + kg + colc;
        const ushort_t* gB1 = gB0 + (size_t)64 * K;

        __syncthreads();
        gl2lds16(gA0, lA0);
        gl2lds16(gA1, lA1);
        gl2lds16(gB0, lB0);
        gl2lds16(gB1, lB1);
        __syncthreads();

        bf16x8 af[4], bfv[4];
#pragma unroll
        for (int i = 0; i < 4; i++) af[i]  = *(const bf16x8*)&As[(wr * 64 + i * 16 + l16) * 32 + quad * 8];
#pragma unroll
        for (int j = 0; j < 4; j++) bfv[j] = *(const bf16x8*)&Bs[(wc * 64 + j * 16 + l16) * 32 + quad * 8];
#pragma unroll
        for (int i = 0; i < 4; i++)
#pragma unroll
            for (int j = 0; j < 4; j++)
                acc[i][j] = __builtin_amdgcn_mfma_f32_16x16x32_bf16(af[i], bfv[j], acc[i][j], 0, 0, 0);
    }

#pragma unroll
    for (int i = 0; i < 4; i++) {
#pragma unroll
        for (int j = 0; j < 4; j++) {
            int r0 = m0 + wr * 64 + i * 16 + quad * 4;
            int c = n0 + wc * 64 + j * 16 + l16;
#pragma unroll
            for (int r = 0; r < 4; r++) {
                float v = acc[i][j][r];
                if (MODE == 1) {
                    size_t o = (size_t)(r0 + r) * 2048 + c;
                    v += bias[c];
                    v = v > 0.0f ? v : 0.0f;
                    outb[o] = f2b(v);
                } else {
                    size_t o = (size_t)(r0 + r) * 256 + c;
                    v += bias[c] + b2f(resb[o]);
                    outf[o] = v;
                }
            }
        }
    }
}

extern "C" void kernel_launch(void* const* d_in, const int* in_sizes, int n_in,
                              void* d_out, int out_size, void* d_ws, size_t ws_size,
                              hipStream_t stream) {
    const float* ent   = (const float*)d_in[0];
    const float* w_in  = (const float*)d_in[1];
    const float* w_out = (const float*)d_in[2];
    const float* W1    = (const float*)d_in[3];
    const float* bias1 = (const float*)d_in[4];
    const float* W2    = (const float*)d_in[5];
    const float* bias2 = (const float*)d_in[6];
    const float* g1    = (const float*)d_in[7];
    const float* be1   = (const float*)d_in[8];
    const float* g2    = (const float*)d_in[9];
    const float* be2   = (const float*)d_in[10];
    float* out = (float*)d_out;

    char* ws = (char*)d_ws;
    // layout (bytes):
    //   xn  bf16 : 16,777,216
    //   yn  bf16 : 16,777,216
    //   xb  bf16 : 16,777,216
    //   h1  bf16 : 134,217,728
    //   bt_in/bt_out/W1b/W2b bf16 : 4 * 1,048,576
    ushort_t* xn     = (ushort_t*)ws;
    ushort_t* yn     = (ushort_t*)(ws + 16777216);
    ushort_t* xb     = (ushort_t*)(ws + 2 * 16777216);
    ushort_t* h1     = (ushort_t*)(ws + 3 * 16777216);
    ushort_t* bt_in  = (ushort_t*)(ws + 3 * 16777216 + 134217728);
    ushort_t* bt_out = bt_in + WELEM;
    ushort_t* W1b    = bt_out + WELEM;
    ushort_t* W2b    = W1b + WELEM;

    // 1) convert + repack all weights to bf16
    hipLaunchKernelGGL(convert_weights, dim3(4 * WELEM / 256), dim3(256), 0, stream,
                       w_in, w_out, W1, W2, bt_in, bt_out, W1b, W2b);
    // 2) LN1: ent -> xn (bf16), one wave per row
    hipLaunchKernelGGL(ln_fast, dim3(M_SZ / 4), dim3(256), 0, stream, ent, g1, be1, xn);
    // 3) TT gemm + fused LN2: yn (bf16), xb (bf16)
    hipLaunchKernelGGL(tt_ln, dim3(M_SZ / 128), dim3(512), 0, stream,
                       xn, bt_in, bt_out, ent, g2, be2, yn, xb);
    // 4) FF1: h1 = relu(yn @ W1b^T + bias1)  (bf16)
    hipLaunchKernelGGL((gemm_k<1, 256>), dim3(16, 256), dim3(256), 0, stream,
                       yn, W1b, bias1, (const ushort_t*)nullptr, (float*)nullptr, h1);
    // 5) FF2: out = xb + h1 @ W2b^T + bias2  (f32)
    hipLaunchKernelGGL((gemm_k<2, 2048>), dim3(2, 256), dim3(256), 0, stream,
                       h1, W2b, bias2, xb, out, (ushort_t*)nullptr);
}